// Round 5
// baseline (375.701 us; speedup 1.0000x reference)
//
#include <hip/hip_runtime.h>
#include <hip/hip_bf16.h>

// ---------------------------------------------------------------------------
// r5: fix latency-bound scheduling.
//   conv1: register-batched LDS staging (7 outstanding loads vs 1)
//   proj:  split-K=8 + f32 atomics into haccum (8 waves/CU vs 2)
//   expert1: 2x2 frags/wave, 2048 single-wave blocks
//   expert2: 1 tile/wave, 1024 blocks
// Outputs (flat f32): logits[256*16] | expert_probs[256*512] | hidden[256*1024]
// ---------------------------------------------------------------------------

#define B_    256
#define CIN   12
#define HH    84
#define WW    84
#define HID   1024
#define NC    16
#define NE    512
#define EPC   64
#define FLAT  3136

typedef short short8 __attribute__((ext_vector_type(8)));
typedef short short4_t __attribute__((ext_vector_type(4)));
typedef float f32x4 __attribute__((ext_vector_type(4)));

__device__ __forceinline__ short f2bf(float x) {   // RNE bf16
    unsigned int u = __float_as_uint(x);
    u = (u + 0x7FFFu + ((u >> 16) & 1u)) >> 16;
    return (short)u;
}

// ============ prep: k1 cast; k2,k3 reorder (oc)(ky,kx,ic) + cast ===========
__global__ __launch_bounds__(256) void prep_weights_kernel(
        const float* __restrict__ k1, const float* __restrict__ k2,
        const float* __restrict__ k3, short* __restrict__ k1bf,
        short* __restrict__ k2t, short* __restrict__ k3t) {
    int i = blockIdx.x * 256 + threadIdx.x;
    if (i < 24576) {                       // k1: layout already (ic,ky,kx)
        k1bf[i] = f2bf(k1[i]);
    } else if (i < 24576 + 32768) {        // k2t[oc][tap16][ic32]
        int j = i - 24576;
        int oc = j >> 9, rem = j & 511, tap = rem >> 5, ic = rem & 31;
        k2t[j] = f2bf(k2[oc * 512 + ic * 16 + tap]);
    } else if (i < 24576 + 32768 + 36864) { // k3t[oc][tap9][ic64]
        int j = i - 57344;
        int oc = j / 576, rem = j % 576, tap = rem >> 6, ic = rem & 63;
        k3t[j] = f2bf(k3[oc * 576 + ic * 9 + tap]);
    }
}

// ======= generic tiled transpose+cast: src f32 [z][R][C] -> dst bf16 [z][C][R]
__global__ __launch_bounds__(256) void transpose_cast_kernel(
        const float* __restrict__ src, short* __restrict__ dst,
        int R, int C, long sbs, long dbs) {
    __shared__ float tile[32][33];
    const int c0 = blockIdx.x * 32, r0 = blockIdx.y * 32, z = blockIdx.z;
    const int tx = threadIdx.x & 31, ty = threadIdx.x >> 5;
    const float* s = src + (size_t)z * sbs;
    short* d = dst + (size_t)z * dbs;
    #pragma unroll
    for (int it = 0; it < 4; ++it)
        tile[ty + it * 8][tx] = s[(size_t)(r0 + ty + it * 8) * C + c0 + tx];
    __syncthreads();
    #pragma unroll
    for (int it = 0; it < 4; ++it) {
        int j = ty + it * 8;               // col of src
        d[(size_t)(c0 + j) * R + r0 + tx] = f2bf(tile[tx][j]);
    }
}

// ========== conv1: LDS-slab implicit GEMM. grid (oyq=4, b=256), 448 thr ====
// Staging: 6048 float4, register-batched: 2 phases x 7 independent loads.
__global__ __launch_bounds__(448) void conv1_mfma_kernel(
        const float* __restrict__ obs, const short* __restrict__ k1bf,
        const float* __restrict__ cb1, short* __restrict__ x1bf) {
    __shared__ short slab[CIN][24][88];
    const int oyq = blockIdx.x, b = blockIdx.y;
    const int tid = threadIdx.x;

    const float* src = obs + (size_t)b * (CIN * HH * WW) + (20 * oyq) * WW;
    short* sl = &slab[0][0][0];
    #pragma unroll
    for (int ph = 0; ph < 2; ++ph) {
        float4 v[7];
        int dsti[7];
        #pragma unroll
        for (int it = 0; it < 7; ++it) {
            int l = ph * 3136 + it * 448 + tid;
            int ok = (l < 6048);
            int li = ok ? l : 6047;              // clamp: load valid dup addr
            int ic = li / 504, rem = li - ic * 504;
            int r = rem / 21, c4 = rem - r * 21;
            v[it] = *(const float4*)(src + (size_t)ic * (HH * WW) + r * WW + 4 * c4);
            dsti[it] = ok ? (ic * (24 * 88) + r * 88 + 4 * c4) : -1;
        }
        #pragma unroll
        for (int it = 0; it < 7; ++it) {
            if (dsti[it] >= 0) {
                short4_t s4v;
                s4v[0] = f2bf(v[it].x); s4v[1] = f2bf(v[it].y);
                s4v[2] = f2bf(v[it].z); s4v[3] = f2bf(v[it].w);
                *(short4_t*)(sl + dsti[it]) = s4v;
            }
        }
    }
    __syncthreads();

    const int w = tid >> 6, l = tid & 63, lr = l & 15, g = l >> 4;
    const int p = w * 16 + lr;
    const int pw = (p < 100) ? p : 99;          // clamp A rows of pad frag
    const int oy_l = pw / 20, ox = pw % 20;
    const short* bb0 = k1bf + lr * 768;
    const short* bb1 = k1bf + (16 + lr) * 768;

    f32x4 acc0 = {0.f, 0.f, 0.f, 0.f}, acc1 = {0.f, 0.f, 0.f, 0.f};
    #pragma unroll 4
    for (int s = 0; s < 24; ++s) {
        const int idx = s * 4 + g;              // (ic,ky)
        const int ic = idx >> 3, ky = idx & 7;
        const short* ap = &slab[ic][4 * oy_l + ky][4 * ox];
        short8 a;
        *(short4_t*)&a       = *(const short4_t*)ap;
        *((short4_t*)&a + 1) = *(const short4_t*)(ap + 4);
        short8 b0 = *(const short8*)(bb0 + s * 32 + g * 8);
        short8 b1 = *(const short8*)(bb1 + s * 32 + g * 8);
        acc0 = __builtin_amdgcn_mfma_f32_16x16x32_bf16(a, b0, acc0, 0, 0, 0);
        acc1 = __builtin_amdgcn_mfma_f32_16x16x32_bf16(a, b1, acc1, 0, 0, 0);
    }
    const float c0v = cb1[lr], c1v = cb1[16 + lr];
    #pragma unroll
    for (int r = 0; r < 4; ++r) {
        const int ro = w * 16 + g * 4 + r;      // pixel in block
        if (ro < 100) {
            const int oy_g = 5 * oyq + ro / 20, ox_g = ro % 20;
            short* dst = x1bf + ((size_t)(b * 20 + oy_g) * 20 + ox_g) * 32;
            dst[lr]      = f2bf(fmaxf(acc0[r] + c0v, 0.f));
            dst[16 + lr] = f2bf(fmaxf(acc1[r] + c1v, 0.f));
        }
    }
}

// ====== conv2: register implicit GEMM. M=20736 N=64 K=512. grid 1296x64 ====
__global__ __launch_bounds__(64) void conv2_mfma_kernel(
        const short* __restrict__ x1bf, const short* __restrict__ k2t,
        const float* __restrict__ cb2, short* __restrict__ x2bf) {
    const int l = threadIdx.x, lr = l & 15, g = l >> 4;
    const int mfb = blockIdx.x * 16;
    const int ro = mfb + lr;
    const int b = ro / 81, pp = ro % 81, oy = pp / 9, ox = pp % 9;
    const short* abase = x1bf + (size_t)b * 12800;

    f32x4 acc[4] = {};
    #pragma unroll 4
    for (int s = 0; s < 16; ++s) {              // tap (ky,kx), 32 ic each
        const int ky = s >> 2, kx = s & 3;
        short8 a = *(const short8*)(abase +
            ((size_t)((2 * oy + ky) * 20 + 2 * ox + kx)) * 32 + g * 8);
        #pragma unroll
        for (int nf = 0; nf < 4; ++nf) {
            short8 bv = *(const short8*)(k2t + (size_t)(nf * 16 + lr) * 512 + s * 32 + g * 8);
            acc[nf] = __builtin_amdgcn_mfma_f32_16x16x32_bf16(a, bv, acc[nf], 0, 0, 0);
        }
    }
    #pragma unroll
    for (int nf = 0; nf < 4; ++nf) {
        const int col = nf * 16 + lr;
        const float bb = cb2[col];
        #pragma unroll
        for (int r = 0; r < 4; ++r) {
            const int roo = mfb + g * 4 + r;
            x2bf[(size_t)roo * 64 + col] = f2bf(fmaxf(acc[nf][r] + bb, 0.f));
        }
    }
}

// ====== conv3: register implicit GEMM. M=12544 N=64 K=576. grid 784x64 =====
__global__ __launch_bounds__(64) void conv3_mfma_kernel(
        const short* __restrict__ x2bf, const short* __restrict__ k3t,
        const float* __restrict__ cb3, short* __restrict__ featsbf) {
    const int l = threadIdx.x, lr = l & 15, g = l >> 4;
    const int mfb = blockIdx.x * 16;
    const int ro = mfb + lr;
    const int b = ro / 49, pp = ro % 49, oy = pp / 7, ox = pp % 7;
    const short* abase = x2bf + (size_t)b * 5184;

    f32x4 acc[4] = {};
    #pragma unroll 4
    for (int s = 0; s < 18; ++s) {              // (tap=s>>1, ic-half=s&1)
        const int tap = s >> 1, ich = s & 1;
        const int ky = tap / 3, kx = tap % 3;
        short8 a = *(const short8*)(abase +
            ((size_t)((oy + ky) * 9 + ox + kx)) * 64 + ich * 32 + g * 8);
        #pragma unroll
        for (int nf = 0; nf < 4; ++nf) {
            short8 bv = *(const short8*)(k3t + (size_t)(nf * 16 + lr) * 576 + s * 32 + g * 8);
            acc[nf] = __builtin_amdgcn_mfma_f32_16x16x32_bf16(a, bv, acc[nf], 0, 0, 0);
        }
    }
    #pragma unroll
    for (int nf = 0; nf < 4; ++nf) {
        const int col = nf * 16 + lr;
        const float bb = cb3[col];
        #pragma unroll
        for (int r = 0; r < 4; ++r) {
            const int roo = mfb + g * 4 + r;
            const int b_o = roo / 49, p_o = roo % 49;
            featsbf[(size_t)b_o * FLAT + col * 49 + p_o] =
                f2bf(fmaxf(acc[nf][r] + bb, 0.f));
        }
    }
}

// ====== proj: split-K=8, atomics. grid (nb=16, mb=16, kz=8), 64 thr ========
// wave: 1 m-frag x 4 n-frags (64 cols), K-chunk ~12 steps. haccum pre-zeroed.
__global__ __launch_bounds__(64) void proj_mfma_kernel(
        const short* __restrict__ Abf, const short* __restrict__ Wt,
        float* __restrict__ haccum) {
    const int l = threadIdx.x, lr = l & 15, g = l >> 4;
    const int n0 = blockIdx.x * 64, m0 = blockIdx.y * 16;
    const int kz = blockIdx.z;
    const int s0 = (kz * 98) >> 3, s1 = ((kz + 1) * 98) >> 3;
    const short* ar = Abf + (size_t)(m0 + lr) * FLAT;
    const short* br0 = Wt + (size_t)(n0 + lr) * FLAT;

    f32x4 acc[4] = {};
    #pragma unroll 2
    for (int s = s0; s < s1; ++s) {
        const int k = s * 32 + g * 8;
        short8 a = *(const short8*)(ar + k);
        #pragma unroll
        for (int nf = 0; nf < 4; ++nf) {
            short8 bv = *(const short8*)(br0 + (size_t)nf * 16 * FLAT + k);
            acc[nf] = __builtin_amdgcn_mfma_f32_16x16x32_bf16(a, bv, acc[nf], 0, 0, 0);
        }
    }
    #pragma unroll
    for (int nf = 0; nf < 4; ++nf)
        #pragma unroll
        for (int r = 0; r < 4; ++r)
            atomicAdd(&haccum[(size_t)(m0 + g * 4 + r) * HID + n0 + nf * 16 + lr],
                      acc[nf][r]);
}

// ===== proj epilogue: hidden = relu(haccum + bproj) -> f32 + bf16 ==========
__global__ __launch_bounds__(256) void proj_epi2_kernel(
        const float* __restrict__ haccum, const float* __restrict__ bproj,
        float* __restrict__ hidden, short* __restrict__ hbf) {
    const int i = blockIdx.x * 256 + threadIdx.x;      // 65536 float4 groups
    float4 v = *(const float4*)&haccum[4 * i];
    float4 bb = *(const float4*)&bproj[(4 * i) & (HID - 1)];
    float4 r;
    r.x = fmaxf(v.x + bb.x, 0.f); r.y = fmaxf(v.y + bb.y, 0.f);
    r.z = fmaxf(v.z + bb.z, 0.f); r.w = fmaxf(v.w + bb.w, 0.f);
    *(float4*)&hidden[4 * i] = r;
    short4_t h; h[0] = f2bf(r.x); h[1] = f2bf(r.y); h[2] = f2bf(r.z); h[3] = f2bf(r.w);
    *(short4_t*)&hbf[4 * i] = h;
}

// ============ category head + softmax (fp32) ===============================
__global__ __launch_bounds__(256) void cat_softmax_kernel(
        const float* __restrict__ hidden, const float* __restrict__ Wcat,
        const float* __restrict__ bcat, float* __restrict__ logits,
        float* __restrict__ probs) {
    __shared__ float red[256];
    __shared__ float lvals[16];
    const int b = blockIdx.x, tid = threadIdx.x;
    const int cc = tid & 15, kq = tid >> 4;
    const float* hrow = hidden + (size_t)b * HID;
    float p = 0.f;
    for (int t = 0; t < 64; ++t) {
        int k = kq * 64 + t;
        p += hrow[k] * Wcat[k * NC + cc];
    }
    red[tid] = p;
    __syncthreads();
    if (tid < 16) {
        float s = bcat[tid];
        #pragma unroll
        for (int q = 0; q < 16; ++q) s += red[q * 16 + tid];
        logits[b * NC + tid] = s;
        lvals[tid] = s;
    }
    __syncthreads();
    if (tid < 16) {
        float m = lvals[0];
        #pragma unroll
        for (int q = 1; q < 16; ++q) m = fmaxf(m, lvals[q]);
        float sum = 0.f;
        #pragma unroll
        for (int q = 0; q < 16; ++q) sum += expf(lvals[q] - m);
        probs[b * NC + tid] = expf(lvals[tid] - m) / sum;
    }
}

// === expert1: h1[c]=relu(hidden@W1[c]+b1[c]). grid (16nb,8mb,16c), 64 thr ==
// wave: 2 m-frags x 2 n-frags (32x32), K=1024.
__global__ __launch_bounds__(64) void expert1_mfma_kernel(
        const short* __restrict__ Hbf, const short* __restrict__ W1t,
        const float* __restrict__ b1, short* __restrict__ h1bf) {
    const int l = threadIdx.x, lr = l & 15, g = l >> 4;
    const int n0 = blockIdx.x * 32, m0 = blockIdx.y * 32, c = blockIdx.z;
    const short* ar0 = Hbf + (size_t)(m0 + lr) * HID;
    const short* ar1 = ar0 + (size_t)16 * HID;
    const short* br0 = W1t + (size_t)c * (512 * HID) + (size_t)(n0 + lr) * HID;
    const short* br1 = br0 + (size_t)16 * HID;

    f32x4 acc[2][2] = {};
    #pragma unroll 4
    for (int s = 0; s < 32; ++s) {
        const int k = s * 32 + g * 8;
        short8 a0 = *(const short8*)(ar0 + k);
        short8 a1 = *(const short8*)(ar1 + k);
        short8 b0v = *(const short8*)(br0 + k);
        short8 b1v = *(const short8*)(br1 + k);
        acc[0][0] = __builtin_amdgcn_mfma_f32_16x16x32_bf16(a0, b0v, acc[0][0], 0, 0, 0);
        acc[0][1] = __builtin_amdgcn_mfma_f32_16x16x32_bf16(a0, b1v, acc[0][1], 0, 0, 0);
        acc[1][0] = __builtin_amdgcn_mfma_f32_16x16x32_bf16(a1, b0v, acc[1][0], 0, 0, 0);
        acc[1][1] = __builtin_amdgcn_mfma_f32_16x16x32_bf16(a1, b1v, acc[1][1], 0, 0, 0);
    }
    #pragma unroll
    for (int j = 0; j < 2; ++j) {
        const int col = n0 + j * 16 + lr;
        const float bb = b1[c * 512 + col];
        #pragma unroll
        for (int i = 0; i < 2; ++i)
            #pragma unroll
            for (int r = 0; r < 4; ++r) {
                const int m = m0 + i * 16 + g * 4 + r;
                h1bf[((size_t)c * B_ + m) * 512 + col] =
                    f2bf(fmaxf(acc[i][j][r] + bb, 0.f));
            }
    }
}

// == expert2: sigmoid(h1@W2+b2)*probs -> atomic scatter. grid (16mb,4nb,16c) =
// wave: 1 tile (16m x 16n), K=512.
__global__ __launch_bounds__(64) void expert2_mfma_kernel(
        const short* __restrict__ h1bf, const short* __restrict__ W2t,
        const float* __restrict__ b2, const float* __restrict__ probs,
        const int* __restrict__ mapping, float* __restrict__ outexp) {
    const int l = threadIdx.x, lr = l & 15, g = l >> 4;
    const int m0 = blockIdx.x * 16, n0 = blockIdx.y * 16, c = blockIdx.z;
    const short* ar = h1bf + ((size_t)c * B_ + m0 + lr) * 512;
    const short* br = W2t + (size_t)c * (EPC * 512) + (size_t)(n0 + lr) * 512;

    f32x4 acc = {};
    #pragma unroll 4
    for (int s = 0; s < 16; ++s) {
        const int k = s * 32 + g * 8;
        short8 a = *(const short8*)(ar + k);
        short8 bv = *(const short8*)(br + k);
        acc = __builtin_amdgcn_mfma_f32_16x16x32_bf16(a, bv, acc, 0, 0, 0);
    }
    const int e = n0 + lr;
    const float bb = b2[c * EPC + e];
    const int tgt = mapping[c * EPC + e];
    #pragma unroll
    for (int r = 0; r < 4; ++r) {
        const int m = m0 + g * 4 + r;
        const float v = probs[m * NC + c] / (1.f + expf(-(acc[r] + bb)));
        atomicAdd(&outexp[(size_t)m * NE + tgt], v);
    }
}

// ===========================================================================
extern "C" void kernel_launch(void* const* d_in, const int* in_sizes, int n_in,
                              void* d_out, int out_size, void* d_ws, size_t ws_size,
                              hipStream_t stream) {
    const float* obs   = (const float*)d_in[0];
    const float* k1    = (const float*)d_in[1];
    const float* cb1   = (const float*)d_in[2];
    const float* k2    = (const float*)d_in[3];
    const float* cb2   = (const float*)d_in[4];
    const float* k3    = (const float*)d_in[5];
    const float* cb3   = (const float*)d_in[6];
    const float* Wproj = (const float*)d_in[7];
    const float* bproj = (const float*)d_in[8];
    const float* Wcat  = (const float*)d_in[9];
    const float* bcat  = (const float*)d_in[10];
    const float* W1    = (const float*)d_in[11];
    const float* b1    = (const float*)d_in[12];
    const float* W2    = (const float*)d_in[13];
    const float* b2    = (const float*)d_in[14];
    const int*   mapping = (const int*)d_in[15];

    float* out    = (float*)d_out;
    float* logits = out;                       // [256*16]
    float* outexp = out + B_ * NC;             // [256*512]
    float* hidden = out + B_ * NC + B_ * NE;   // [256*1024]

    // ws choreography (peak 20.7MB <= proven 22.7MB):
    //  [0,16.8M): x1bf@0 (6.55M) -> Wprojt@0 (6.42M, after conv2)
    //             -> W1t@0 (16.78M, after proj_epi) -> W2t@0 (after e1)
    //             x2bf@6.55M (2.65M, dead after conv3) -> haccum@6.55M (1M)
    //             featsbf@9.21M (1.61M, dead after proj)
    //  [16.8M,20.7M): hidbf, probs, k1bf, k2t, k3t, h1bf
    char* ws = (char*)d_ws;
    short* x1bf    = (short*)ws;
    short* Wprojt  = (short*)ws;
    short* W1t     = (short*)ws;
    short* W2t     = (short*)ws;
    short* x2bf    = (short*)(ws + 6553600);
    float* haccum  = (float*)(ws + 6553600);   // alias x2bf (dead after conv3)
    short* featsbf = (short*)(ws + 9207808);
    short* hidbf   = (short*)(ws + 16777216);
    float* probs   = (float*)(ws + 17301504);
    short* k1bf    = (short*)(ws + 17317888);
    short* k2t     = (short*)(ws + 17367040);
    short* k3t     = (short*)(ws + 17432576);
    short* h1bf    = (short*)(ws + 17506304);

    hipMemsetAsync(outexp, 0, (size_t)B_ * NE * sizeof(float), stream);

    prep_weights_kernel<<<dim3(368), 256, 0, stream>>>(k1, k2, k3, k1bf, k2t, k3t);
    conv1_mfma_kernel<<<dim3(4, B_), 448, 0, stream>>>(obs, k1bf, cb1, x1bf);
    conv2_mfma_kernel<<<dim3(1296), 64, 0, stream>>>(x1bf, k2t, cb2, x2bf);
    // Wprojt overwrites x1bf: after conv2.
    transpose_cast_kernel<<<dim3(32, 98, 1), 256, 0, stream>>>(
        Wproj, Wprojt, FLAT, HID, 0, 0);
    conv3_mfma_kernel<<<dim3(784), 64, 0, stream>>>(x2bf, k3t, cb3, featsbf);
    // haccum aliases x2bf: zero only after conv3 consumed it.
    hipMemsetAsync(haccum, 0, (size_t)B_ * HID * sizeof(float), stream);
    proj_mfma_kernel<<<dim3(16, 16, 8), 64, 0, stream>>>(featsbf, Wprojt, haccum);
    proj_epi2_kernel<<<dim3(256), 256, 0, stream>>>(haccum, bproj, hidden, hidbf);
    cat_softmax_kernel<<<dim3(B_), 256, 0, stream>>>(hidden, Wcat, bcat, logits, probs);
    // W1t overwrites Wprojt/haccum/featsbf: after proj_epi.
    transpose_cast_kernel<<<dim3(16, 32, 16), 256, 0, stream>>>(
        W1, W1t, HID, 512, (long)HID * 512, (long)HID * 512);
    expert1_mfma_kernel<<<dim3(16, 8, 16), 64, 0, stream>>>(hidbf, W1t, b1, h1bf);
    // W2t overwrites W1t: after expert1.
    transpose_cast_kernel<<<dim3(2, 16, 16), 256, 0, stream>>>(
        W2, W2t, 512, EPC, (long)512 * EPC, (long)512 * EPC);
    expert2_mfma_kernel<<<dim3(16, 4, 16), 64, 0, stream>>>(
        h1bf, W2t, b2, probs, mapping, outexp);
}